// Round 2
// baseline (229.654 us; speedup 1.0000x reference)
//
#include <hip/hip_runtime.h>

// Sparsemax over last dim, rows of N=512 fp32.
// One 64-lane wave solves RPW=4 independent rows CONCURRENTLY (dual-state in
// registers, 8 elements/lane/row). Rationale: the solver is a serial
// dependency chain (DPP reduction -> readlane -> divide -> compare), measured
// latency-bound (VALUBusy 34%, HBM 31%, dur unchanged when VALU work was cut
// 2.4x). Four independent rows per wave give the scheduler 4 interleavable
// instances of every chain element and cut wave count 4x.
//
// Each row keeps the SAME 64-lane layout and DPP summation tree as the
// 1-row/wave version -> bitwise-identical tau -> absmax stays 0.0.
//
// tau via Michelot fixed-point iteration, warm-started at tau = z_max - 1
// (provable lower bound on tau*), support count via __ballot + s_bcnt1 (SALU).

#define ROW_N 512
#define LANES 64
#define EPL 8  // elements per lane per row
#define RPW 4  // rows per wave (dual-state ILP)

// One DPP step: v = v + dpp_move(v). bound_ctrl=1 -> out-of-bounds lanes read 0
// (additive identity).
#define DPP_ADD_STEP(v, ctrl, rmask)                                        \
  v += __int_as_float(__builtin_amdgcn_update_dpp(                          \
      0, __float_as_int(v), ctrl, rmask, 0xf, true))

// Full-wave (64-lane) sum; returns the total, uniform across the wave.
__device__ inline float wave_sum64(float v) {
  DPP_ADD_STEP(v, 0x111, 0xf);  // row_shr:1
  DPP_ADD_STEP(v, 0x112, 0xf);  // row_shr:2
  DPP_ADD_STEP(v, 0x114, 0xf);  // row_shr:4
  DPP_ADD_STEP(v, 0x118, 0xf);  // row_shr:8  -> lane15 of each row = row sum
  DPP_ADD_STEP(v, 0x142, 0xa);  // row_bcast:15 -> lanes 31, 63 accumulate
  DPP_ADD_STEP(v, 0x143, 0xc);  // row_bcast:31 -> lane 63 = wave total
  return __int_as_float(__builtin_amdgcn_readlane(__float_as_int(v), 63));
}

// Full-wave max: identity-old variant (invalid/masked lanes contribute v).
#define DPP_MAX_STEP(v, ctrl, rmask)                                        \
  v = fmaxf(v, __int_as_float(__builtin_amdgcn_update_dpp(                  \
             __float_as_int(v), __float_as_int(v), ctrl, rmask, 0xf, false)))

__device__ inline float wave_max64(float v) {
  DPP_MAX_STEP(v, 0x111, 0xf);
  DPP_MAX_STEP(v, 0x112, 0xf);
  DPP_MAX_STEP(v, 0x114, 0xf);
  DPP_MAX_STEP(v, 0x118, 0xf);
  DPP_MAX_STEP(v, 0x142, 0xa);
  DPP_MAX_STEP(v, 0x143, 0xc);
  return __int_as_float(__builtin_amdgcn_readlane(__float_as_int(v), 63));
}

__global__ __launch_bounds__(256) void sparsemax_kernel(
    const float* __restrict__ x, float* __restrict__ out, int nrows) {
  const int lane = threadIdx.x & 63;
  const int wave = threadIdx.x >> 6;
  const int wid = blockIdx.x * 4 + wave;
  const int row0 = wid * RPW;
  if (row0 >= nrows) return;

  // Clamp OOB rows to a valid address; their stores are skipped below.
  int rr[RPW];
#pragma unroll
  for (int r = 0; r < RPW; ++r) rr[r] = min(row0 + r, nrows - 1);

  // Issue all 8 float4 loads up front (max MLP, one HBM round trip).
  float z[RPW][EPL];
#pragma unroll
  for (int r = 0; r < RPW; ++r) {
    const float4* xr = (const float4*)(x + (size_t)rr[r] * ROW_N);
    float4 a = xr[lane];
    float4 b = xr[lane + LANES];
    z[r][0] = a.x; z[r][1] = a.y; z[r][2] = a.z; z[r][3] = a.w;
    z[r][4] = b.x; z[r][5] = b.y; z[r][6] = b.z; z[r][7] = b.w;
  }

  // Row max (stability shift) — 4 independent DPP chains, interleavable.
  float m[RPW];
#pragma unroll
  for (int r = 0; r < RPW; ++r) {
    float mm = z[r][0];
#pragma unroll
    for (int i = 1; i < EPL; ++i) mm = fmaxf(mm, z[r][i]);
    m[r] = mm;
  }
#pragma unroll
  for (int r = 0; r < RPW; ++r) m[r] = wave_max64(m[r]);
#pragma unroll
  for (int r = 0; r < RPW; ++r)
#pragma unroll
    for (int i = 0; i < EPL; ++i) z[r][i] -= m[r];

  // Michelot with warm start tau = z_max - 1 = -1 (tau* >= -1 provably).
  // All 4 rows iterate together; iterating a converged row is idempotent
  // (same support -> bitwise-same tau), so running to max(iter_r) is safe.
  float tau[RPW] = {-1.0f, -1.0f, -1.0f, -1.0f};
  int pc[RPW] = {-1, -1, -1, -1};
  for (int iter = 0; iter < 64; ++iter) {
    float ls[RPW];
    int cnt[RPW];
#pragma unroll
    for (int r = 0; r < RPW; ++r) {
      float s = 0.0f;
      int c = 0;
#pragma unroll
      for (int i = 0; i < EPL; ++i) {
        bool g = z[r][i] > tau[r];
        c += (int)__popcll(__ballot(g));  // SALU: s_bcnt1 + s_add
        s += g ? z[r][i] : 0.0f;          // VALU: cndmask + add
      }
      ls[r] = s;
      cnt[r] = c;
    }
    // 4 independent 6-step DPP sum chains — scheduler interleaves them.
#pragma unroll
    for (int r = 0; r < RPW; ++r) ls[r] = wave_sum64(ls[r]);
    bool allstable = true;
#pragma unroll
    for (int r = 0; r < RPW; ++r) {
      tau[r] = (ls[r] - 1.0f) / (float)cnt[r];  // 4 independent IEEE divs
      allstable = allstable && (cnt[r] == pc[r]);
      pc[r] = cnt[r];
    }
    if (allstable) break;  // all supports stable -> all taus are fixed points
  }

#pragma unroll
  for (int r = 0; r < RPW; ++r) {
    if (row0 + r < nrows) {
      float4* outr = (float4*)(out + (size_t)rr[r] * ROW_N);
      float4 oa = {fmaxf(z[r][0] - tau[r], 0.0f), fmaxf(z[r][1] - tau[r], 0.0f),
                   fmaxf(z[r][2] - tau[r], 0.0f), fmaxf(z[r][3] - tau[r], 0.0f)};
      float4 ob = {fmaxf(z[r][4] - tau[r], 0.0f), fmaxf(z[r][5] - tau[r], 0.0f),
                   fmaxf(z[r][6] - tau[r], 0.0f), fmaxf(z[r][7] - tau[r], 0.0f)};
      outr[lane] = oa;
      outr[lane + LANES] = ob;
    }
  }
}

extern "C" void kernel_launch(void* const* d_in, const int* in_sizes, int n_in,
                              void* d_out, int out_size, void* d_ws,
                              size_t ws_size, hipStream_t stream) {
  const float* x = (const float*)d_in[0];
  float* out = (float*)d_out;
  const int nrows = in_sizes[0] / ROW_N;
  const int nwaves = (nrows + RPW - 1) / RPW;
  const int blocks = (nwaves + 3) / 4;
  sparsemax_kernel<<<blocks, 256, 0, stream>>>(x, out, nrows);
}